// Round 1
// baseline (187.559 us; speedup 1.0000x reference)
//
#include <hip/hip_runtime.h>

#define GAMMA 0.3f

struct Ctl {
  int posCount;       // number of target==1 rows
  int negCount;       // number of target!=1 rows
  unsigned doneCount; // pair-kernel completion counter
  int pad;
  double accum;       // global sum of margin^2
};

// Kernel 1: per-row 2-way softmax score + wave-aggregated compaction into
// pos[] / neg[] score lists.
__global__ void score_compact_kernel(const float2* __restrict__ inp,
                                     const int* __restrict__ target,
                                     float* __restrict__ posS,
                                     float* __restrict__ negS,
                                     Ctl* ctl, int n) {
  int i = blockIdx.x * blockDim.x + threadIdx.x;
  if (i >= n) return;

  float2 x = inp[i];
  // softmax(x)[1] = 1 / (1 + exp(x0 - x1))
  float s = 1.0f / (1.0f + expf(x.x - x.y));
  bool isPos = (target[i] == 1);

  unsigned long long act = __ballot(1);      // active lanes (full wave when n%64==0)
  unsigned long long bal = __ballot(isPos);
  int lane = threadIdx.x & 63;
  unsigned long long lt = (lane == 63) ? 0x7fffffffffffffffull
                                       : ((1ull << lane) - 1ull);
  int nPos = __popcll(bal);
  int nNeg = __popcll(act & ~bal);
  int myPosIdx = __popcll(bal & lt);
  int myNegIdx = __popcll(act & ~bal & lt);

  int basePos = 0, baseNeg = 0;
  if (lane == 0) {
    basePos = atomicAdd(&ctl->posCount, nPos);
    baseNeg = atomicAdd(&ctl->negCount, nNeg);
  }
  basePos = __shfl(basePos, 0);
  baseNeg = __shfl(baseNeg, 0);

  if (isPos) posS[basePos + myPosIdx] = s;
  else       negS[baseNeg + myNegIdx] = s;
}

// Kernel 2: sum over (neg i, pos j) of max(gamma - (s_j - s_i), 0)^2.
// Blocks stride negatives; threads stride positives (pos array is L1/L2
// resident: ~32 KB). Last finished block writes the final scalar.
__global__ void pair_kernel(const float* __restrict__ posS,
                            const float* __restrict__ negS,
                            Ctl* ctl, float* __restrict__ out, int n) {
  const int posCount = ctl->posCount;
  const int negCount = ctl->negCount;

  float acc = 0.0f;
  for (int nn = blockIdx.x; nn < negCount; nn += gridDim.x) {
    const float t = GAMMA + negS[nn];           // margin = t - s_pos
    for (int j = threadIdx.x; j < posCount; j += blockDim.x) {
      float m = t - posS[j];
      m = fmaxf(m, 0.0f);                       // mask: diff < gamma  <=>  m > 0
      acc = fmaf(m, m, acc);
    }
  }

  // wave reduce (64 lanes)
  for (int o = 32; o > 0; o >>= 1) acc += __shfl_down(acc, o);

  __shared__ float red[8];
  int wid = threadIdx.x >> 6;
  int lane = threadIdx.x & 63;
  if (lane == 0) red[wid] = acc;
  __syncthreads();

  if (threadIdx.x == 0) {
    float b = 0.0f;
    int nw = blockDim.x >> 6;
    for (int w = 0; w < nw; ++w) b += red[w];
    atomicAdd(&ctl->accum, (double)b);
    __threadfence();
    unsigned done = atomicAdd(&ctl->doneCount, 1u);
    if (done == gridDim.x - 1) {
      __threadfence();
      // atomic RMW readback => coherent across XCD L2s
      double total = atomicAdd(&ctl->accum, 0.0);
      *out = (float)(total / (double)n);
    }
  }
}

extern "C" void kernel_launch(void* const* d_in, const int* in_sizes, int n_in,
                              void* d_out, int out_size, void* d_ws, size_t ws_size,
                              hipStream_t stream) {
  const float2* inp  = (const float2*)d_in[0]; // [N,2] f32
  const int* target  = (const int*)d_in[1];    // [N] int
  const int n = in_sizes[1];                   // N rows

  float* posS = (float*)d_ws;
  float* negS = posS + n;
  Ctl* ctl = (Ctl*)((char*)d_ws + (size_t)2 * n * sizeof(float));

  hipMemsetAsync(ctl, 0, sizeof(Ctl), stream);

  int blocks1 = (n + 255) / 256;
  score_compact_kernel<<<blocks1, 256, 0, stream>>>(inp, target, posS, negS, ctl, n);

  pair_kernel<<<256, 256, 0, stream>>>(posS, negS, ctl, (float*)d_out, n);
}

// Round 3
// 91.758 us; speedup vs baseline: 2.0441x; 2.0441x over previous
//
#include <hip/hip_runtime.h>

#define GAMMA 0.3f
#define K2_BLOCKS 1024
#define K2_THREADS 256
#define ROWS 16        // K2_BLOCKS * ROWS == N == 16384

struct Ctl {
  unsigned doneCount;
  unsigned pad;
  double accum;
};

// Kernel 1: sentinel score arrays (no atomics, no compaction) + ctl init.
//   P[i]  = s_i          if target==1 else +1e30   (pos scores)
//   Nn[i] = s_i + gamma  if target!=1 else -1e30   (neg thresholds)
// Sentinels make masked pairs contribute exactly 0 via fmax(.,0).
__global__ void prep_kernel(const float2* __restrict__ inp,
                            const int* __restrict__ target,
                            float* __restrict__ P,
                            float* __restrict__ Nn,
                            Ctl* ctl, int n) {
  int i = blockIdx.x * blockDim.x + threadIdx.x;
  if (i == 0) {
    atomicExch(&ctl->doneCount, 0u);
    atomicExch((unsigned long long*)&ctl->accum, 0ull); // accum = 0.0
  }
  if (i >= n) return;
  float2 x = inp[i];
  float s = 1.0f / (1.0f + expf(x.x - x.y));  // softmax(x)[1]
  bool isPos = (target[i] == 1);
  P[i]  = isPos ? s : 1e30f;
  Nn[i] = isPos ? -1e30f : s + GAMMA;
}

// Kernel 2: sum over all (i,j) of max(Nn[i] - P[j], 0)^2.
// Block owns ROWS rows of Nn (held in registers); threads stride P with
// float4 (64 KB, L2-resident). 64 independent acc chains per thread.
__global__ __launch_bounds__(K2_THREADS)
void pair_kernel(const float* __restrict__ P,
                 const float* __restrict__ Nn,
                 Ctl* ctl, float* __restrict__ out, int n) {
  float tn[ROWS];
  const int rbase = blockIdx.x * ROWS;
#pragma unroll
  for (int k = 0; k < ROWS; ++k) {
    int r = rbase + k;
    tn[k] = (r < n) ? Nn[r] : -1e30f;
  }

  const float4* P4 = (const float4*)P;
  const int n4 = n >> 2;
  float a0 = 0.f, a1 = 0.f, a2 = 0.f, a3 = 0.f;
  for (int jb = threadIdx.x; jb < n4; jb += K2_THREADS) {
    float4 pb = P4[jb];
#pragma unroll
    for (int k = 0; k < ROWS; ++k) {
      float m0 = fmaxf(tn[k] - pb.x, 0.f); a0 = fmaf(m0, m0, a0);
      float m1 = fmaxf(tn[k] - pb.y, 0.f); a1 = fmaf(m1, m1, a1);
      float m2 = fmaxf(tn[k] - pb.z, 0.f); a2 = fmaf(m2, m2, a2);
      float m3 = fmaxf(tn[k] - pb.w, 0.f); a3 = fmaf(m3, m3, a3);
    }
  }
  float acc = (a0 + a1) + (a2 + a3);

  // wave reduce (64 lanes)
  for (int o = 32; o > 0; o >>= 1) acc += __shfl_down(acc, o);

  __shared__ float red[K2_THREADS / 64];
  const int wid = threadIdx.x >> 6;
  const int lane = threadIdx.x & 63;
  if (lane == 0) red[wid] = acc;
  __syncthreads();

  if (threadIdx.x == 0) {
    float b = red[0] + red[1] + red[2] + red[3];
    atomicAdd(&ctl->accum, (double)b);
    __threadfence();
    unsigned done = atomicAdd(&ctl->doneCount, 1u);
    if (done == gridDim.x - 1) {
      __threadfence();
      double total = atomicAdd(&ctl->accum, 0.0);  // coherent RMW readback
      *out = (float)(total / (double)n);
    }
  }
}

extern "C" void kernel_launch(void* const* d_in, const int* in_sizes, int n_in,
                              void* d_out, int out_size, void* d_ws, size_t ws_size,
                              hipStream_t stream) {
  const float2* inp  = (const float2*)d_in[0]; // [N,2] f32
  const int* target  = (const int*)d_in[1];    // [N] int
  const int n = in_sizes[1];

  float* P  = (float*)d_ws;
  float* Nn = P + n;
  Ctl* ctl  = (Ctl*)(Nn + n);   // 8-byte aligned (2*n*4 bytes offset)

  int blocks1 = (n + 255) / 256;
  prep_kernel<<<blocks1, 256, 0, stream>>>(inp, target, P, Nn, ctl, n);

  pair_kernel<<<K2_BLOCKS, K2_THREADS, 0, stream>>>(P, Nn, ctl, (float*)d_out, n);
}